// Round 7
// baseline (347.343 us; speedup 1.0000x reference)
//
#include <hip/hip_runtime.h>
#include <math.h>

#define BATCH 4096
#define SEQ_T 512
#define ISZ   4
#define HID   64
#define OSZ   40
#define RPB   16

typedef __attribute__((ext_vector_type(8))) _Float16     half8;
typedef __attribute__((ext_vector_type(2))) _Float16     half2v;
typedef __attribute__((ext_vector_type(4))) float        float4v;
typedef __attribute__((ext_vector_type(2))) unsigned int uint2v;

static __device__ __forceinline__ half2v pk_f16(float a, float b) {
    return __builtin_bit_cast(half2v, __builtin_amdgcn_cvt_pkrtz(a, b));
}
static __device__ __forceinline__ float fast_tanh(float x) {
    float e = __expf(2.0f * x);
    return 1.0f - 2.0f * __builtin_amdgcn_rcpf(e + 1.0f);
}

__global__ __launch_bounds__(256, 1)
void rnn_pair_kernel(const float* __restrict__ x,
                     const float* __restrict__ W_ih,
                     const float* __restrict__ W_hh,
                     const float* __restrict__ b_ih,
                     const float* __restrict__ b_hh,
                     const float* __restrict__ fc_W,
                     const float* __restrict__ fc_b,
                     float* __restrict__ out)
{
    // B-fragment-native h storage: [term][g][n][j] = h_term[k=8g+j], batch col n.
    __shared__ __attribute__((aligned(16))) _Float16 hsh[2][2][8][16][8];   // even-step h, dbuf/pair
    __shared__ __attribute__((aligned(16))) _Float16 hpv[4][2][8][16][8];   // odd-step h, per-wave private
    __shared__ __attribute__((aligned(16))) float hf[16][68];

    const int tid  = threadIdx.x;
    const int wv   = tid >> 6;
    const int lane = tid & 63;
    const int n    = lane & 15;
    const int q    = lane >> 4;
    const int blk0 = blockIdx.x * RPB;
    const int j0   = 4 * (q & 1);

    {   // h(0) = 0
        unsigned int* p = (unsigned int*)hsh;
        #pragma unroll
        for (int i = tid; i < (int)(sizeof(hsh) / 4); i += 256) p[i] = 0u;
    }

    // ---- A fragments for ALL 4 M-tiles (phase A computes full M=64) ----
    half8 A1c0[4], A1c1[4], A2c0[4], A2c1[4], A3[4];
    #pragma unroll
    for (int g = 0; g < 4; ++g) {
        const float* wr = W_hh + (16 * g + n) * HID;
        #pragma unroll
        for (int j = 0; j < 8; ++j) {
            float f0 = wr[     8 * q + j];
            float f1 = wr[32 + 8 * q + j];
            _Float16 h0 = (_Float16)f0; A1c0[g][j] = h0; A2c0[g][j] = (_Float16)(f0 - (float)h0);
            _Float16 h1 = (_Float16)f1; A1c1[g][j] = h1; A2c1[g][j] = (_Float16)(f1 - (float)h1);
        }
        // A3: xproj+bias MFMA operand. q0: j0-3 Whi, j4-7 Whi; q1: j0-3 Wlo, j4 bias_hi, j5 bias_lo.
        float wf0 = W_ih[(16*g+n)*4+0], wf1 = W_ih[(16*g+n)*4+1];
        float wf2 = W_ih[(16*g+n)*4+2], wf3 = W_ih[(16*g+n)*4+3];
        float bs  = b_ih[16*g+n] + b_hh[16*g+n];
        _Float16 bh = (_Float16)bs;
        _Float16 bl = (_Float16)(bs - (float)bh);
        #pragma unroll
        for (int j = 0; j < 8; ++j) {
            float w = (j&3)==0 ? wf0 : (j&3)==1 ? wf1 : (j&3)==2 ? wf2 : wf3;
            _Float16 whi = (_Float16)w;
            _Float16 wlo = (_Float16)(w - (float)whi);
            _Float16 v = (_Float16)0.0f;
            if (q == 0) v = whi;
            else if (q == 1) v = (j < 4) ? wlo : (j == 4) ? bh : (j == 5) ? bl : (_Float16)0.0f;
            A3[g][j] = v;
        }
    }
    // phase-B duplicates for own tile (avoid dynamic register indexing)
    half8 AB1c0, AB1c1, AB2c0, AB2c1, AB3;
    {
        const float* wr = W_hh + (16 * wv + n) * HID;
        #pragma unroll
        for (int j = 0; j < 8; ++j) {
            float f0 = wr[     8 * q + j];
            float f1 = wr[32 + 8 * q + j];
            _Float16 h0 = (_Float16)f0; AB1c0[j] = h0; AB2c0[j] = (_Float16)(f0 - (float)h0);
            _Float16 h1 = (_Float16)f1; AB1c1[j] = h1; AB2c1[j] = (_Float16)(f1 - (float)h1);
        }
        float wf0 = W_ih[(16*wv+n)*4+0], wf1 = W_ih[(16*wv+n)*4+1];
        float wf2 = W_ih[(16*wv+n)*4+2], wf3 = W_ih[(16*wv+n)*4+3];
        float bs  = b_ih[16*wv+n] + b_hh[16*wv+n];
        _Float16 bh = (_Float16)bs;
        _Float16 bl = (_Float16)(bs - (float)bh);
        #pragma unroll
        for (int j = 0; j < 8; ++j) {
            float w = (j&3)==0 ? wf0 : (j&3)==1 ? wf1 : (j&3)==2 ? wf2 : wf3;
            _Float16 whi = (_Float16)w;
            _Float16 wlo = (_Float16)(w - (float)whi);
            _Float16 v = (_Float16)0.0f;
            if (q == 0) v = whi;
            else if (q == 1) v = (j < 4) ? wlo : (j == 4) ? bh : (j == 5) ? bl : (_Float16)0.0f;
            AB3[j] = v;
        }
    }

    const float* xrow = x + (size_t)(blk0 + n) * SEQ_T * ISZ;
    float4v xc0 = *(const float4v*)(xrow);
    float4v xc1 = *(const float4v*)(xrow + ISZ);

    float hl0 = 0.f, hl1 = 0.f, hl2 = 0.f, hl3 = 0.f;

    const unsigned int ONE2 = 0x3C003C00u;  // (1.0h, 1.0h)

    __syncthreads();

#define MFMA16(A, B, C) __builtin_amdgcn_mfma_f32_16x16x32_f16((A), (B), (C), 0, 0, 0)
// build B3 operand from fp32 x4: q0: [xhi|xlo], q1: [xhi|1,1], else 0
#define BUILD_B3(DST, XV)                                                      \
    {                                                                          \
        half2v xh01 = pk_f16((XV)[0], (XV)[1]), xh23 = pk_f16((XV)[2], (XV)[3]); \
        float l0 = (XV)[0] - (float)xh01[0], l1 = (XV)[1] - (float)xh01[1];    \
        float l2 = (XV)[2] - (float)xh23[0], l3 = (XV)[3] - (float)xh23[1];    \
        half2v xl01 = pk_f16(l0, l1), xl23 = pk_f16(l2, l3);                   \
        unsigned int uh01 = __builtin_bit_cast(unsigned int, xh01);            \
        unsigned int uh23 = __builtin_bit_cast(unsigned int, xh23);            \
        unsigned int ul01 = __builtin_bit_cast(unsigned int, xl01);            \
        unsigned int ul23 = __builtin_bit_cast(unsigned int, xl23);            \
        unsigned int d0 = (q < 2) ? uh01 : 0u;                                 \
        unsigned int d1 = (q < 2) ? uh23 : 0u;                                 \
        unsigned int d2 = (q == 0) ? ul01 : (q == 1) ? ONE2 : 0u;              \
        unsigned int d3 = (q == 0) ? ul23 : 0u;                                \
        unsigned int tmp[4] = {d0, d1, d2, d3};                                \
        DST = *(half8*)tmp;                                                    \
    }

#define PAIR(RB, WB, P)                                                        \
    {                                                                          \
        int t2 = 2*(P) + 2; if (t2 > SEQ_T - 1) t2 = SEQ_T - 1;                \
        int t3 = 2*(P) + 3; if (t3 > SEQ_T - 1) t3 = SEQ_T - 1;                \
        const float4v xf0 = *(const float4v*)(xrow + (size_t)t2 * ISZ);        \
        const float4v xf1 = *(const float4v*)(xrow + (size_t)t3 * ISZ);        \
        /* ---- phase A: step 2P, full M=64, write private ---- */             \
        half8 B10 = *(const half8*)&hsh[RB][0][    q][n][0];                   \
        half8 B11 = *(const half8*)&hsh[RB][0][4 + q][n][0];                   \
        half8 B20 = *(const half8*)&hsh[RB][1][    q][n][0];                   \
        half8 B21 = *(const half8*)&hsh[RB][1][4 + q][n][0];                   \
        half8 B3a; BUILD_B3(B3a, xc0)                                          \
        _Pragma("unroll")                                                      \
        for (int g = 0; g < 4; ++g) {                                          \
            float4v aA = {0.f, 0.f, 0.f, 0.f};                                 \
            float4v aB = {0.f, 0.f, 0.f, 0.f};                                 \
            aB = MFMA16(A3[g],   B3a, aB);                                     \
            aA = MFMA16(A1c0[g], B10, aA);                                     \
            aB = MFMA16(A1c1[g], B11, aB);                                     \
            aA = MFMA16(A1c0[g], B20, aA);                                     \
            aB = MFMA16(A1c1[g], B21, aB);                                     \
            aA = MFMA16(A2c0[g], B10, aA);                                     \
            aB = MFMA16(A2c1[g], B11, aB);                                     \
            float v0 = fast_tanh(aA[0] + aB[0]);                               \
            float v1 = fast_tanh(aA[1] + aB[1]);                               \
            float v2 = fast_tanh(aA[2] + aB[2]);                               \
            float v3 = fast_tanh(aA[3] + aB[3]);                               \
            half2v hi01 = pk_f16(v0, v1), hi23 = pk_f16(v2, v3);               \
            float s0 = v0 - (float)hi01[0], s1 = v1 - (float)hi01[1];          \
            float s2 = v2 - (float)hi23[0], s3 = v3 - (float)hi23[1];          \
            half2v lo01 = pk_f16(s0, s1), lo23 = pk_f16(s2, s3);               \
            uint2v whi = { __builtin_bit_cast(unsigned int, hi01),             \
                           __builtin_bit_cast(unsigned int, hi23) };           \
            uint2v wlo = { __builtin_bit_cast(unsigned int, lo01),             \
                           __builtin_bit_cast(unsigned int, lo23) };           \
            *(uint2v*)&hpv[wv][0][2*g + (q >> 1)][n][j0] = whi;                \
            *(uint2v*)&hpv[wv][1][2*g + (q >> 1)][n][j0] = wlo;                \
        }                                                                      \
        /* ---- phase B: step 2P+1, own tile, read private (same wave) ---- */ \
        half8 C10 = *(const half8*)&hpv[wv][0][    q][n][0];                   \
        half8 C11 = *(const half8*)&hpv[wv][0][4 + q][n][0];                   \
        half8 C20 = *(const half8*)&hpv[wv][1][    q][n][0];                   \
        half8 C21 = *(const half8*)&hpv[wv][1][4 + q][n][0];                   \
        half8 B3b; BUILD_B3(B3b, xc1)                                          \
        float4v aA = {0.f, 0.f, 0.f, 0.f};                                     \
        float4v aB = {0.f, 0.f, 0.f, 0.f};                                     \
        aB = MFMA16(AB3,   B3b, aB);                                           \
        aA = MFMA16(AB1c0, C10, aA);                                           \
        aB = MFMA16(AB1c1, C11, aB);                                           \
        aA = MFMA16(AB1c0, C20, aA);                                           \
        aB = MFMA16(AB1c1, C21, aB);                                           \
        aA = MFMA16(AB2c0, C10, aA);                                           \
        aB = MFMA16(AB2c1, C11, aB);                                           \
        hl0 = fast_tanh(aA[0] + aB[0]);                                        \
        hl1 = fast_tanh(aA[1] + aB[1]);                                        \
        hl2 = fast_tanh(aA[2] + aB[2]);                                        \
        hl3 = fast_tanh(aA[3] + aB[3]);                                        \
        half2v hi01 = pk_f16(hl0, hl1), hi23 = pk_f16(hl2, hl3);               \
        float s0 = hl0 - (float)hi01[0], s1 = hl1 - (float)hi01[1];            \
        float s2 = hl2 - (float)hi23[0], s3 = hl3 - (float)hi23[1];            \
        half2v lo01 = pk_f16(s0, s1), lo23 = pk_f16(s2, s3);                   \
        uint2v whi = { __builtin_bit_cast(unsigned int, hi01),                 \
                       __builtin_bit_cast(unsigned int, hi23) };               \
        uint2v wlo = { __builtin_bit_cast(unsigned int, lo01),                 \
                       __builtin_bit_cast(unsigned int, lo23) };               \
        *(uint2v*)&hsh[WB][0][2*wv + (q >> 1)][n][j0] = whi;                   \
        *(uint2v*)&hsh[WB][1][2*wv + (q >> 1)][n][j0] = wlo;                   \
        xc0 = xf0; xc1 = xf1;                                                  \
        __syncthreads();                                                       \
    }

    for (int p = 0; p < SEQ_T / 2; p += 2) {
        PAIR(0, 1, p)
        PAIR(1, 0, p + 1)
    }
#undef PAIR
#undef BUILD_B3
#undef MFMA16

    // ---- fc epilogue on fp32 final h ----
    {
        float4v hv = {hl0, hl1, hl2, hl3};
        *(float4v*)&hf[n][16 * wv + 4 * q] = hv;
    }
    __syncthreads();
    for (int it = tid; it < RPB * OSZ; it += 256) {
        const int b = it / OSZ;
        const int o = it - b * OSZ;
        const float* wo = fc_W + o * HID;
        float acc = fc_b[o];
        #pragma unroll
        for (int j = 0; j < HID; ++j)
            acc = fmaf(hf[b][j], wo[j], acc);
        out[(size_t)(blk0 + b) * OSZ + o] = acc;
    }
}

extern "C" void kernel_launch(void* const* d_in, const int* in_sizes, int n_in,
                              void* d_out, int out_size, void* d_ws, size_t ws_size,
                              hipStream_t stream) {
    const float* x    = (const float*)d_in[0];
    const float* W_ih = (const float*)d_in[1];
    const float* W_hh = (const float*)d_in[2];
    const float* b_ih = (const float*)d_in[3];
    const float* b_hh = (const float*)d_in[4];
    const float* fc_W = (const float*)d_in[5];
    const float* fc_b = (const float*)d_in[6];
    float* out = (float*)d_out;

    rnn_pair_kernel<<<BATCH / RPB, 256, 0, stream>>>(
        x, W_ih, W_hh, b_ih, b_hh, fc_W, fc_b, out);
}

// Round 8
// 282.516 us; speedup vs baseline: 1.2295x; 1.2295x over previous
//
#include <hip/hip_runtime.h>
#include <math.h>

#define BATCH 4096
#define SEQ_T 512
#define ISZ   4
#define HID   64
#define OSZ   40
#define RPB   8      // 8 valid batch cols per block -> 512 blocks = 2 per CU (TLP vs chain)

typedef __attribute__((ext_vector_type(8))) _Float16     half8;
typedef __attribute__((ext_vector_type(2))) _Float16     half2v;
typedef __attribute__((ext_vector_type(4))) float        float4v;
typedef __attribute__((ext_vector_type(2))) unsigned int uint2v;

static __device__ __forceinline__ half2v pk_f16(float a, float b) {
    return __builtin_bit_cast(half2v, __builtin_amdgcn_cvt_pkrtz(a, b)); // v_cvt_pkrtz_f16_f32
}

// tanh(x) = 1 - 2/(exp(2x)+1); saturates to +/-1, NaN-free
static __device__ __forceinline__ float fast_tanh(float x) {
    float e = __expf(2.0f * x);
    return 1.0f - 2.0f * __builtin_amdgcn_rcpf(e + 1.0f);
}

__global__ __launch_bounds__(256, 2)
void rnn_f16x2b_kernel(const float* __restrict__ x,
                       const float* __restrict__ W_ih,
                       const float* __restrict__ W_hh,
                       const float* __restrict__ b_ih,
                       const float* __restrict__ b_hh,
                       const float* __restrict__ fc_W,
                       const float* __restrict__ fc_b,
                       float* __restrict__ out)
{
    // h terms in B-fragment-native order: hterm[buf][tau][g][n][j] = h_tau[k=8g+j] for batch col n.
    // Reader lane(n,q): b128 at [tau][4c+q][n][0] -> banks (4n+d)%32, 2-way (free, m136).
    // Writer lane(n,q) wave w: rows 16w+4q+r -> g=2w+(q>>1), j0=4(q&1): one b64 per term, 2-way.
    __shared__ __attribute__((aligned(16))) _Float16 hterm[2][2][8][16][8];
    __shared__ __attribute__((aligned(16))) float hf[16][68];

    const int tid  = threadIdx.x;
    const int wv   = tid >> 6;
    const int lane = tid & 63;
    const int n    = lane & 15;    // A: row m; B/C/D: batch col n (cols 8..15 mirror 0..7)
    const int q    = lane >> 4;
    const int blk0 = blockIdx.x * RPB;

    // h(0) = 0: zero both buffers
    {
        unsigned int* p = (unsigned int*)hterm;
        #pragma unroll
        for (int i = tid; i < (int)(sizeof(hterm) / 4); i += 256) p[i] = 0u;
    }

    // ---- static A fragments: W_hh row 16wv+n, 2-term fp16 split, K-chunks c=0,1 ----
    half8 A10, A11, A20, A21;   // A1x = hi term, A2x = residual term
    {
        const float* wr = W_hh + (16 * wv + n) * HID;
        #pragma unroll
        for (int j = 0; j < 8; ++j) {
            float f0 = wr[     8 * q + j];
            float f1 = wr[32 + 8 * q + j];
            _Float16 h0 = (_Float16)f0; A10[j] = h0; A20[j] = (_Float16)(f0 - (float)h0);
            _Float16 h1 = (_Float16)f1; A11[j] = h1; A21[j] = (_Float16)(f1 - (float)h1);
        }
    }

    // ---- fp32 x-projection weights + bias for C rows 16wv + 4q + r ----
    const int r0 = 16 * wv + 4 * q;
    float wih[4][4], bias[4];
    #pragma unroll
    for (int r = 0; r < 4; ++r) {
        bias[r] = b_ih[r0 + r] + b_hh[r0 + r];
        #pragma unroll
        for (int i = 0; i < ISZ; ++i) wih[r][i] = W_ih[(r0 + r) * ISZ + i];
    }

    // ---- per-lane x pipeline (fp32 from global; cols 8..15 mirror 0..7 -> L1 broadcast) ----
    const float* xrow = x + (size_t)(blk0 + (n & 7)) * SEQ_T * ISZ;
    float4v xcur = *(const float4v*)(xrow);
    float4v xnxt = *(const float4v*)(xrow + ISZ);

    const int gw = 2 * wv + (q >> 1);
    const int j0 = 4 * (q & 1);

    float hl0 = 0.f, hl1 = 0.f, hl2 = 0.f, hl3 = 0.f;

    __syncthreads();   // zero-init visible

#define MFMA16(A, B, C) __builtin_amdgcn_mfma_f32_16x16x32_f16((A), (B), (C), 0, 0, 0)
#define RNN_STEP(RB, WB, T)                                                    \
    {                                                                          \
        int tn = (T) + 2; if (tn > SEQ_T - 1) tn = SEQ_T - 1;                  \
        const float4v xf = *(const float4v*)(xrow + (size_t)tn * ISZ);         \
        half8 B10 = *(const half8*)&hterm[RB][0][    q][n][0];                 \
        half8 B11 = *(const half8*)&hterm[RB][0][4 + q][n][0];                 \
        half8 B20 = *(const half8*)&hterm[RB][1][    q][n][0];                 \
        half8 B21 = *(const half8*)&hterm[RB][1][4 + q][n][0];                 \
        float p0 = bias[0], p1 = bias[1], p2 = bias[2], p3 = bias[3];          \
        _Pragma("unroll")                                                      \
        for (int i = 0; i < ISZ; ++i) {                                        \
            p0 = fmaf(xcur[i], wih[0][i], p0);                                 \
            p1 = fmaf(xcur[i], wih[1][i], p1);                                 \
            p2 = fmaf(xcur[i], wih[2][i], p2);                                 \
            p3 = fmaf(xcur[i], wih[3][i], p3);                                 \
        }                                                                      \
        float4v accA = {p0, p1, p2, p3};                                       \
        float4v accB = {0.f, 0.f, 0.f, 0.f};                                   \
        accA = MFMA16(A10, B10, accA);  accB = MFMA16(A11, B11, accB);         \
        accA = MFMA16(A10, B20, accA);  accB = MFMA16(A11, B21, accB);         \
        accA = MFMA16(A20, B10, accA);  accB = MFMA16(A21, B11, accB);         \
        hl0 = fast_tanh(accA[0] + accB[0]); hl1 = fast_tanh(accA[1] + accB[1]);\
        hl2 = fast_tanh(accA[2] + accB[2]); hl3 = fast_tanh(accA[3] + accB[3]);\
        half2v hi01 = pk_f16(hl0, hl1), hi23 = pk_f16(hl2, hl3);               \
        float s0 = hl0 - (float)hi01[0], s1 = hl1 - (float)hi01[1];            \
        float s2 = hl2 - (float)hi23[0], s3 = hl3 - (float)hi23[1];            \
        half2v lo01 = pk_f16(s0, s1), lo23 = pk_f16(s2, s3);                   \
        uint2v whi = { __builtin_bit_cast(unsigned int, hi01),                 \
                       __builtin_bit_cast(unsigned int, hi23) };               \
        uint2v wlo = { __builtin_bit_cast(unsigned int, lo01),                 \
                       __builtin_bit_cast(unsigned int, lo23) };               \
        *(uint2v*)&hterm[WB][0][gw][n][j0] = whi;                              \
        *(uint2v*)&hterm[WB][1][gw][n][j0] = wlo;                              \
        xcur = xnxt; xnxt = xf;                                                \
        __syncthreads();                                                       \
    }

    for (int t = 0; t < SEQ_T; t += 2) {
        RNN_STEP(0, 1, t)
        RNN_STEP(1, 0, t + 1)
    }
#undef RNN_STEP
#undef MFMA16

    // ---- fc epilogue on fp32 final h (in registers) ----
    {
        float4v hv = {hl0, hl1, hl2, hl3};
        *(float4v*)&hf[n][16 * wv + 4 * q] = hv;
    }
    __syncthreads();
    for (int it = tid; it < RPB * OSZ; it += 256) {
        const int b = it / OSZ;
        const int o = it - b * OSZ;
        const float* wo = fc_W + o * HID;
        float acc = fc_b[o];
        #pragma unroll
        for (int j = 0; j < HID; ++j)
            acc = fmaf(hf[b][j], wo[j], acc);
        out[(size_t)(blk0 + b) * OSZ + o] = acc;
    }
}

extern "C" void kernel_launch(void* const* d_in, const int* in_sizes, int n_in,
                              void* d_out, int out_size, void* d_ws, size_t ws_size,
                              hipStream_t stream) {
    const float* x    = (const float*)d_in[0];
    const float* W_ih = (const float*)d_in[1];
    const float* W_hh = (const float*)d_in[2];
    const float* b_ih = (const float*)d_in[3];
    const float* b_hh = (const float*)d_in[4];
    const float* fc_W = (const float*)d_in[5];
    const float* fc_b = (const float*)d_in[6];
    float* out = (float*)d_out;

    rnn_f16x2b_kernel<<<BATCH / RPB, 256, 0, stream>>>(
        x, W_ih, W_hh, b_ih, b_hh, fc_W, fc_b, out);
}